// Round 1
// 96.394 us; speedup vs baseline: 1.0016x; 1.0016x over previous
//
#include <hip/hip_runtime.h>
#include <math.h>

// CRF forward: B=64, C=2, T=65536.
// Log-semiring matrix scan: alpha_t = A_t (x) alpha_{t-1},
//   A_t[i][j] = trans[i][j] + emit_t[i]
// Associative => parallel chunked scan with 2x2 transfer matrices.
// All math in base-2 logs so LSE = 1x v_exp_f32 + 1x v_log_f32.

#define T_LEN   65536
#define SEG     4096      // elements per block
#define CH_L    16        // elements per thread chunk
#define NT      256       // threads per block
#define NSEG    16        // SEG * NSEG = T_LEN
#define NBATCH  64

// __builtin_amdgcn_exp2f = v_exp_f32 (2^x); __builtin_amdgcn_logf = v_log_f32 (log2 x)
__device__ __forceinline__ float lse2(float a, float b) {
    float m = fmaxf(a, b);
    float d = fminf(a, b) - m;          // <= 0; -1e30 inputs give exp2 -> 0, no NaN
    return m + __builtin_amdgcn_logf(1.0f + __builtin_amdgcn_exp2f(d));
}

// 16-byte store with only 4-byte alignment guarantee (dec = out+1 is 4 mod 16).
// packed+aligned(4) lets the compiler emit global_store_dwordx4 align-4 instead
// of 4 scalar dword stores.
struct __attribute__((packed, aligned(4))) F4 { float x, y, z, w; };

__global__ __launch_bounds__(NT) void crf_scan_kernel(
    const float* __restrict__ logits,   // (B, 2, T) flat
    const float* __restrict__ trans,    // (2,2)
    float* __restrict__ out,            // out[0]=loss, out[1..]=decoded
    float4* __restrict__ wsM)           // 1024 chunk matrices, [seg][batch]
{
    // emissions interleaved as float2 (state0, state1): one ds_read_b64 per
    // element instead of 2x ds_read_b32. +1 float2 pad per 16 keeps the
    // stride-17 reads at the structural bank minimum (verified: word index
    // 34*tid+2j -> each of 32 banks gets exactly 4 of the 128 words).
    __shared__ float2 sE[SEG + SEG / 16];
    __shared__ float4 red4[NT / 64];    // one matrix per wave after butterfly

    const int blk = blockIdx.x;         // 0..1023
    const int b   = blk >> 4;           // batch
    const int seg = blk & (NSEG - 1);   // segment within batch
    const int tid = threadIdx.x;
    const float K = 1.4426950408889634f;    // log2(e)

    const float* l0 = logits + (size_t)b * (2 * T_LEN) + (size_t)seg * SEG;
    const float* l1 = l0 + T_LEN;
    float* dec = out + 1 + (size_t)b * T_LEN + (size_t)seg * SEG;

    // ---- Phase A: coalesced load -> LDS (scaled to base-2), fused argmax write ----
    #pragma unroll
    for (int it = 0; it < SEG / (NT * 4); ++it) {   // 4 iterations
        const int idx = it * NT * 4 + tid * 4;
        const float4 a = *(const float4*)(l0 + idx);
        const float4 c = *(const float4*)(l1 + idx);
        F4 dv;
        dv.x = (a.x >= c.x) ? 0.0f : 1.0f;
        dv.y = (a.y >= c.y) ? 0.0f : 1.0f;
        dv.z = (a.z >= c.z) ? 0.0f : 1.0f;
        dv.w = (a.w >= c.w) ? 0.0f : 1.0f;
        __builtin_memcpy(dec + idx, &dv, sizeof(F4));   // 1 dwordx4 store
        const int li = idx + (idx >> 4);    // swizzle: groups of 4 stay contiguous
        sE[li + 0] = make_float2(a.x * K, c.x * K);
        sE[li + 1] = make_float2(a.y * K, c.y * K);
        sE[li + 2] = make_float2(a.z * K, c.z * K);
        sE[li + 3] = make_float2(a.w * K, c.w * K);
    }

    const float t00 = trans[0] * K, t01 = trans[1] * K;
    const float t10 = trans[2] * K, t11 = trans[3] * K;
    __syncthreads();

    // ---- Phase B: per-thread sequential scan over CH_L steps (2x2 matrix mode) ----
    const int lb = tid * 17;            // == (tid*16) + ((tid*16)>>4), in float2 units
    float2 e = sE[lb];
    float m00, m01, m10, m11;
    if (seg == 0 && tid == 0) {
        // global t=0: initial vector alpha0 = emit_0 as diagonal "matrix"
        m00 = e.x; m11 = e.y; m01 = -1e30f; m10 = -1e30f;
    } else {
        m00 = t00 + e.x; m01 = t01 + e.x;
        m10 = t10 + e.y; m11 = t11 + e.y;
    }
    #pragma unroll
    for (int j = 1; j < CH_L; ++j) {
        e = sE[lb + j];
        float n00 = e.x + lse2(t00 + m00, t01 + m10);
        float n01 = e.x + lse2(t00 + m01, t01 + m11);
        float n10 = e.y + lse2(t10 + m00, t11 + m10);
        float n11 = e.y + lse2(t10 + m01, t11 + m11);
        m00 = n00; m01 = n01; m10 = n10; m11 = n11;
    }

    // ---- Phase C: in-wave butterfly reduce (non-commutative, order-selected).
    // Adjacent-pair association: at step s, lane's 2s-block product is
    // later∘earlier chosen by (lane & s). Replaces 8 strided LDS rounds with
    // 16 barrier crossings by 6 shfl rounds + 1 barrier.
    const int lane = tid & 63;
    #pragma unroll
    for (int s = 1; s < 64; s <<= 1) {
        float px = __shfl_xor(m00, s);
        float py = __shfl_xor(m01, s);
        float pz = __shfl_xor(m10, s);
        float pw = __shfl_xor(m11, s);
        const bool up = (lane & s) != 0;    // our block is the LATER half
        float lx = up ? m00 : px, ly = up ? m01 : py;
        float lz = up ? m10 : pz, lw = up ? m11 : pw;
        float ex = up ? px : m00, ey = up ? py : m01;
        float ez = up ? pz : m10, ew = up ? pw : m11;
        m00 = lse2(lx + ex, ly + ez);
        m01 = lse2(lx + ey, ly + ew);
        m10 = lse2(lz + ex, lw + ez);
        m11 = lse2(lz + ey, lw + ew);
    }
    if (lane == 0) red4[tid >> 6] = make_float4(m00, m01, m10, m11);
    __syncthreads();
    if (tid == 0) {
        // compose 4 wave results: M = (W3∘W2)∘(W1∘W0)  (two independent pairs)
        float4 A = red4[0], Bv = red4[1], Cv = red4[2], Dv = red4[3];
        float4 P01, P23, M;
        P01.x = lse2(Bv.x + A.x, Bv.y + A.z);
        P01.y = lse2(Bv.x + A.y, Bv.y + A.w);
        P01.z = lse2(Bv.z + A.x, Bv.w + A.z);
        P01.w = lse2(Bv.z + A.y, Bv.w + A.w);
        P23.x = lse2(Dv.x + Cv.x, Dv.y + Cv.z);
        P23.y = lse2(Dv.x + Cv.y, Dv.y + Cv.w);
        P23.z = lse2(Dv.z + Cv.x, Dv.w + Cv.z);
        P23.w = lse2(Dv.z + Cv.y, Dv.w + Cv.w);
        M.x = lse2(P23.x + P01.x, P23.y + P01.z);
        M.y = lse2(P23.x + P01.y, P23.y + P01.w);
        M.z = lse2(P23.z + P01.x, P23.w + P01.z);
        M.w = lse2(P23.z + P01.y, P23.w + P01.w);
        wsM[seg * NBATCH + b] = M;      // [seg][batch] so final kernel coalesces
    }
}

__global__ __launch_bounds__(64) void crf_final_kernel(
    const float4* __restrict__ wsM, float* __restrict__ out)
{
    const int b = threadIdx.x;          // one lane per batch, exactly one wave
    float4 M[NSEG];
    #pragma unroll
    for (int s = 0; s < NSEG; ++s) M[s] = wsM[s * NBATCH + b];  // coalesced
    // pairwise tree: chain depth 4 instead of 15, pairs independent (ILP)
    #pragma unroll
    for (int n = NSEG / 2; n >= 1; n >>= 1) {
        #pragma unroll
        for (int i = 0; i < n; ++i) {
            float4 E = M[2 * i], L = M[2 * i + 1];  // L is later in time
            float4 R;
            R.x = lse2(L.x + E.x, L.y + E.z);
            R.y = lse2(L.x + E.y, L.y + E.w);
            R.z = lse2(L.z + E.x, L.w + E.z);
            R.w = lse2(L.z + E.y, L.w + E.w);
            M[i] = R;
        }
    }
    // alpha_final[i] = LSE_k M[i][k]; LL2_b = LSE_i alpha_final[i]
    float ll2 = lse2(lse2(M[0].x, M[0].y), lse2(M[0].z, M[0].w));
    #pragma unroll
    for (int off = 32; off >= 1; off >>= 1) ll2 += __shfl_xor(ll2, off);
    if (b == 0) out[0] = -(0.6931471805599453f * ll2) * (1.0f / (float)NBATCH);
}

extern "C" void kernel_launch(void* const* d_in, const int* in_sizes, int n_in,
                              void* d_out, int out_size, void* d_ws, size_t ws_size,
                              hipStream_t stream) {
    const float* logits = (const float*)d_in[0];
    // d_in[1] = mask: all-ones and unused by the reference computation
    const float* trans  = (const float*)d_in[2];
    float* out  = (float*)d_out;
    float4* wsM = (float4*)d_ws;    // 1024 * 16 B = 16 KiB

    crf_scan_kernel<<<NBATCH * NSEG, NT, 0, stream>>>(logits, trans, out, wsM);
    crf_final_kernel<<<1, 64, 0, stream>>>(wsM, out);
}